// Round 1
// baseline (3386.169 us; speedup 1.0000x reference)
//
#include <hip/hip_runtime.h>
#include <math.h>

// Problem constants
#define Bn  2
#define Sn  2048
#define Hn  2048
#define NHn 16
#define HDn 128
#define Mn  (Bn * Sn)   // 4096
#define Kd  Hn          // 2048 (GEMM inner dim)

// ---------------- fp32 GEMM core: C[m][n] = sum_k A[m][k] * W[n][k] ----------------
#define BM  128
#define BN  128
#define BKc 16
#define LDT 136   // padded LDS row stride (floats); 136 mod 32 = 8 -> 2-way max on stores

__device__ __forceinline__ void gemm_core(const float* __restrict__ A,
                                          const float* __restrict__ W,
                                          int m0, int n0, float acc[8][8],
                                          float As[BKc][LDT], float Bs[BKc][LDT])
{
    const int t  = threadIdx.x;
    const int ty = t >> 4, tx = t & 15;
    for (int k0 = 0; k0 < Kd; k0 += BKc) {
        // Stage A tile (128x16) and B tile (128x16), k-major in LDS.
        #pragma unroll
        for (int it = 0; it < 2; ++it) {
            int ff  = t + it * 256;          // 0..511 quad index
            int row = ff >> 2;               // 0..127
            int kq  = (ff & 3) << 2;         // 0,4,8,12
            float4 a4 = *(const float4*)&A[(size_t)(m0 + row) * Kd + k0 + kq];
            As[kq + 0][row] = a4.x; As[kq + 1][row] = a4.y;
            As[kq + 2][row] = a4.z; As[kq + 3][row] = a4.w;
            float4 b4 = *(const float4*)&W[(size_t)(n0 + row) * Kd + k0 + kq];
            Bs[kq + 0][row] = b4.x; Bs[kq + 1][row] = b4.y;
            Bs[kq + 2][row] = b4.z; Bs[kq + 3][row] = b4.w;
        }
        __syncthreads();
        #pragma unroll
        for (int k = 0; k < BKc; ++k) {
            float4 a0 = *(const float4*)&As[k][ty * 8];
            float4 a1 = *(const float4*)&As[k][ty * 8 + 4];
            float4 b0 = *(const float4*)&Bs[k][tx * 8];
            float4 b1 = *(const float4*)&Bs[k][tx * 8 + 4];
            float a[8] = {a0.x, a0.y, a0.z, a0.w, a1.x, a1.y, a1.z, a1.w};
            float b[8] = {b0.x, b0.y, b0.z, b0.w, b1.x, b1.y, b1.z, b1.w};
            #pragma unroll
            for (int i = 0; i < 8; ++i)
                #pragma unroll
                for (int j = 0; j < 8; ++j)
                    acc[i][j] = fmaf(a[i], b[j], acc[i][j]);
        }
        __syncthreads();
    }
}

// ---------------- QKV projection + RoPE, writes (b, h, s, d) layout ----------------
__global__ __launch_bounds__(256)
void qkv_rope_kernel(const float* __restrict__ x,
                     const float* __restrict__ Wq, const float* __restrict__ Wk,
                     const float* __restrict__ Wv,
                     const float* __restrict__ fcos, const float* __restrict__ fsin,
                     float* __restrict__ q_ws, float* __restrict__ k_ws,
                     float* __restrict__ v_ws)
{
    __shared__ float As[BKc][LDT];
    __shared__ float Bs[BKc][LDT];
    const int mode = blockIdx.z;                 // 0=Q 1=K 2=V
    const float* W = (mode == 0) ? Wq : (mode == 1) ? Wk : Wv;
    float* outp    = (mode == 0) ? q_ws : (mode == 1) ? k_ws : v_ws;
    const int m0 = blockIdx.x * BM;
    const int n0 = blockIdx.y * BN;

    float acc[8][8];
    #pragma unroll
    for (int i = 0; i < 8; ++i)
        #pragma unroll
        for (int j = 0; j < 8; ++j) acc[i][j] = 0.f;

    gemm_core(x, W, m0, n0, acc, As, Bs);

    const int t = threadIdx.x, ty = t >> 4, tx = t & 15;
    const int h = n0 >> 7;          // n0 is a multiple of 128 -> whole block is one head
    #pragma unroll
    for (int i = 0; i < 8; ++i) {
        int m  = m0 + ty * 8 + i;
        int bb = m >> 11;           // m / S
        int s  = m & (Sn - 1);
        float* dst = &outp[(((size_t)bb * NHn + h) * Sn + s) * HDn + tx * 8];
        if (mode < 2) {
            #pragma unroll
            for (int j = 0; j < 8; j += 2) {
                int d   = tx * 8 + j;                 // even
                float c  = fcos[s * (HDn / 2) + (d >> 1)];
                float sn = fsin[s * (HDn / 2) + (d >> 1)];
                float2 w;
                w.x = acc[i][j] * c  - acc[i][j + 1] * sn;
                w.y = acc[i][j] * sn + acc[i][j + 1] * c;
                *(float2*)&dst[j] = w;
            }
        } else {
            float4 w0 = {acc[i][0], acc[i][1], acc[i][2], acc[i][3]};
            float4 w1 = {acc[i][4], acc[i][5], acc[i][6], acc[i][7]};
            *(float4*)&dst[0] = w0;
            *(float4*)&dst[4] = w1;
        }
    }
}

// ---------------- Output projection ----------------
__global__ __launch_bounds__(256)
void oproj_kernel(const float* __restrict__ A, const float* __restrict__ Wo,
                  float* __restrict__ out)
{
    __shared__ float As[BKc][LDT];
    __shared__ float Bs[BKc][LDT];
    const int m0 = blockIdx.x * BM;
    const int n0 = blockIdx.y * BN;
    float acc[8][8];
    #pragma unroll
    for (int i = 0; i < 8; ++i)
        #pragma unroll
        for (int j = 0; j < 8; ++j) acc[i][j] = 0.f;

    gemm_core(A, Wo, m0, n0, acc, As, Bs);

    const int t = threadIdx.x, ty = t >> 4, tx = t & 15;
    #pragma unroll
    for (int i = 0; i < 8; ++i) {
        int m = m0 + ty * 8 + i;
        float* dst = &out[(size_t)m * Hn + n0 + tx * 8];
        float4 w0 = {acc[i][0], acc[i][1], acc[i][2], acc[i][3]};
        float4 w1 = {acc[i][4], acc[i][5], acc[i][6], acc[i][7]};
        *(float4*)&dst[0] = w0;
        *(float4*)&dst[4] = w1;
    }
}

// ---------------- Flash attention (fp32, causal + padding mask) ----------------
#define BQ  64
#define BKV 32
#define QLD 132   // 132 mod 32 = 4 -> row-spread banks, 16B-aligned rows
#define KLD 132
#define PLD 68    // 68 mod 32 = 4, 16B-aligned rows
#define ATTN_SMEM_FLOATS (BQ * QLD + BKV * KLD + BQ * PLD)
#define ATTN_SMEM_BYTES  (ATTN_SMEM_FLOATS * 4)   // 68096 B

__global__ __launch_bounds__(256)
void attn_kernel(const float* __restrict__ q_ws, const float* __restrict__ k_ws,
                 const float* __restrict__ v_ws, const int* __restrict__ pmask,
                 float* __restrict__ attn_out)
{
    extern __shared__ float smem[];
    float* Qs  = smem;                 // [BQ][QLD]
    float* KVs = smem + BQ * QLD;      // [BKV][KLD]  (K then V, time-shared)
    float* Ps  = KVs + BKV * KLD;      // [BQ][PLD]

    const int qt = blockIdx.x, h = blockIdx.y, b = blockIdx.z;
    const int q0 = qt * BQ;
    const size_t base = (size_t)(b * NHn + h) * Sn * HDn;
    const float* Qp = q_ws + base;
    const float* Kp = k_ws + base;
    const float* Vp = v_ws + base;
    const int t = threadIdx.x, ty = t >> 4, tx = t & 15;

    // Stage the Q tile (64 x 128)
    #pragma unroll
    for (int it = 0; it < 8; ++it) {
        int f = t + it * 256;
        int r = f >> 5, c4 = (f & 31) << 2;
        *(float4*)&Qs[r * QLD + c4] = *(const float4*)&Qp[(size_t)(q0 + r) * HDn + c4];
    }

    float o[4][8];
    #pragma unroll
    for (int i = 0; i < 4; ++i)
        #pragma unroll
        for (int d = 0; d < 8; ++d) o[i][d] = 0.f;
    float mrow[4], lrow[4];
    #pragma unroll
    for (int i = 0; i < 4; ++i) { mrow[i] = -1e30f; lrow[i] = 0.f; }

    const float scale = 0.08838834764831845f;   // 1/sqrt(128)
    const int ntiles = (q0 + BQ) / BKV;         // causal: only tiles touching kg <= qg

    for (int kt = 0; kt < ntiles; ++kt) {
        const int kv0 = kt * BKV;
        __syncthreads();   // previous PV's V reads complete (also covers Q staging)
        // Stage K tile (32 x 128)
        #pragma unroll
        for (int it = 0; it < 4; ++it) {
            int f = t + it * 256;
            int r = f >> 5, c4 = (f & 31) << 2;
            *(float4*)&KVs[r * KLD + c4] =
                *(const float4*)&Kp[(size_t)(kv0 + r) * HDn + c4];
        }
        __syncthreads();

        // Scores: rows ty*4+i, cols {tx, tx+16}
        float sc[4][2] = {{0.f,0.f},{0.f,0.f},{0.f,0.f},{0.f,0.f}};
        #pragma unroll 8
        for (int d0 = 0; d0 < HDn; d0 += 4) {
            float4 k0q = *(const float4*)&KVs[tx * KLD + d0];
            float4 k1q = *(const float4*)&KVs[(tx + 16) * KLD + d0];
            #pragma unroll
            for (int i = 0; i < 4; ++i) {
                float4 qv = *(const float4*)&Qs[(ty * 4 + i) * QLD + d0];
                sc[i][0] += qv.x*k0q.x + qv.y*k0q.y + qv.z*k0q.z + qv.w*k0q.w;
                sc[i][1] += qv.x*k1q.x + qv.y*k1q.y + qv.z*k1q.z + qv.w*k1q.w;
            }
        }

        // Mask + online softmax
        float pm[2];
        pm[0] = pmask[b * Sn + kv0 + tx]      ? 0.f : -10000.f;
        pm[1] = pmask[b * Sn + kv0 + tx + 16] ? 0.f : -10000.f;
        float tmax[4];
        #pragma unroll
        for (int i = 0; i < 4; ++i) {
            int qg = q0 + ty * 4 + i;
            #pragma unroll
            for (int j = 0; j < 2; ++j) {
                int kg = kv0 + tx + 16 * j;
                float v = sc[i][j] * scale + pm[j];
                if (kg > qg) v += -1e9f;
                sc[i][j] = v;
            }
            tmax[i] = fmaxf(sc[i][0], sc[i][1]);
        }
        #pragma unroll
        for (int off = 1; off < 16; off <<= 1) {
            #pragma unroll
            for (int i = 0; i < 4; ++i)
                tmax[i] = fmaxf(tmax[i], __shfl_xor(tmax[i], off));
        }
        float tsum[4];
        #pragma unroll
        for (int i = 0; i < 4; ++i) {
            float mnew = fmaxf(mrow[i], tmax[i]);
            float sf   = __expf(mrow[i] - mnew);
            mrow[i] = mnew;
            lrow[i] *= sf;
            #pragma unroll
            for (int d = 0; d < 8; ++d) o[i][d] *= sf;
            float p0 = __expf(sc[i][0] - mnew);
            float p1 = __expf(sc[i][1] - mnew);
            Ps[(ty * 4 + i) * PLD + tx]      = p0;
            Ps[(ty * 4 + i) * PLD + tx + 16] = p1;
            tsum[i] = p0 + p1;
        }
        #pragma unroll
        for (int off = 1; off < 16; off <<= 1) {
            #pragma unroll
            for (int i = 0; i < 4; ++i)
                tsum[i] += __shfl_xor(tsum[i], off);
        }
        #pragma unroll
        for (int i = 0; i < 4; ++i) lrow[i] += tsum[i];

        __syncthreads();   // Ps written; K reads done
        // Stage V tile into the same buffer
        #pragma unroll
        for (int it = 0; it < 4; ++it) {
            int f = t + it * 256;
            int r = f >> 5, c4 = (f & 31) << 2;
            *(float4*)&KVs[r * KLD + c4] =
                *(const float4*)&Vp[(size_t)(kv0 + r) * HDn + c4];
        }
        __syncthreads();

        // O += P @ V : rows ty*4+i, d-cols tx*8..tx*8+7
        #pragma unroll 2
        for (int c0 = 0; c0 < BKV; c0 += 4) {
            float4 pq[4];
            #pragma unroll
            for (int i = 0; i < 4; ++i)
                pq[i] = *(const float4*)&Ps[(ty * 4 + i) * PLD + c0];
            #pragma unroll
            for (int cc = 0; cc < 4; ++cc) {
                float4 v0 = *(const float4*)&KVs[(c0 + cc) * KLD + tx * 8];
                float4 v1 = *(const float4*)&KVs[(c0 + cc) * KLD + tx * 8 + 4];
                #pragma unroll
                for (int i = 0; i < 4; ++i) {
                    float p = (cc == 0) ? pq[i].x : (cc == 1) ? pq[i].y
                             : (cc == 2) ? pq[i].z : pq[i].w;
                    o[i][0] = fmaf(p, v0.x, o[i][0]);
                    o[i][1] = fmaf(p, v0.y, o[i][1]);
                    o[i][2] = fmaf(p, v0.z, o[i][2]);
                    o[i][3] = fmaf(p, v0.w, o[i][3]);
                    o[i][4] = fmaf(p, v1.x, o[i][4]);
                    o[i][5] = fmaf(p, v1.y, o[i][5]);
                    o[i][6] = fmaf(p, v1.z, o[i][6]);
                    o[i][7] = fmaf(p, v1.w, o[i][7]);
                }
            }
        }
    }

    // Normalize + write (b, s, h*HD + d) layout
    #pragma unroll
    for (int i = 0; i < 4; ++i) {
        int s = q0 + ty * 4 + i;
        float inv = 1.0f / lrow[i];
        float* dst = &attn_out[((size_t)b * Sn + s) * Hn + h * HDn + tx * 8];
        float4 w0 = {o[i][0]*inv, o[i][1]*inv, o[i][2]*inv, o[i][3]*inv};
        float4 w1 = {o[i][4]*inv, o[i][5]*inv, o[i][6]*inv, o[i][7]*inv};
        *(float4*)&dst[0] = w0;
        *(float4*)&dst[4] = w1;
    }
}

// ---------------- launch ----------------
extern "C" void kernel_launch(void* const* d_in, const int* in_sizes, int n_in,
                              void* d_out, int out_size, void* d_ws, size_t ws_size,
                              hipStream_t stream)
{
    const float* x     = (const float*)d_in[0];
    const float* fcos  = (const float*)d_in[1];
    const float* fsin  = (const float*)d_in[2];
    const int*   pmask = (const int*)d_in[3];
    const float* Wq    = (const float*)d_in[4];
    const float* Wk    = (const float*)d_in[5];
    const float* Wv    = (const float*)d_in[6];
    const float* Wo    = (const float*)d_in[7];
    float* out = (float*)d_out;

    const size_t per = (size_t)Bn * NHn * Sn * HDn;   // 8,388,608 floats each
    float* q_ws = (float*)d_ws;
    float* k_ws = q_ws + per;
    float* v_ws = k_ws + per;
    float* attn = v_ws + per;
    (void)in_sizes; (void)n_in; (void)out_size; (void)ws_size;

    // Opt in to >64KB dynamic LDS for the attention kernel (gfx950: 160KB/CU).
    hipFuncSetAttribute((const void*)attn_kernel,
                        hipFuncAttributeMaxDynamicSharedMemorySize, ATTN_SMEM_BYTES);

    dim3 blk(256);
    qkv_rope_kernel<<<dim3(Mn / BM, Hn / BN, 3), blk, 0, stream>>>(
        x, Wq, Wk, Wv, fcos, fsin, q_ws, k_ws, v_ws);
    attn_kernel<<<dim3(Sn / BQ, NHn, Bn), blk, ATTN_SMEM_BYTES, stream>>>(
        q_ws, k_ws, v_ws, pmask, attn);
    oproj_kernel<<<dim3(Mn / BM, Hn / BN, 1), blk, 0, stream>>>(attn, Wo, out);
}

// Round 3
// 532.733 us; speedup vs baseline: 6.3562x; 6.3562x over previous
//
#include <hip/hip_runtime.h>
#include <math.h>

// Problem constants
#define Bn  2
#define Sn  2048
#define Hn  2048
#define NHn 16
#define HDn 128
#define Mn  (Bn * Sn)   // 4096
#define Kd  Hn          // 2048

typedef __attribute__((ext_vector_type(8))) short bf16x8;   // 8 bf16 in 4 VGPRs
typedef __attribute__((ext_vector_type(4))) float fx4;

__device__ __forceinline__ unsigned short f2bf(float f) {
    union { float f; unsigned u; } v; v.f = f;
    unsigned r = v.u + 0x7fffu + ((v.u >> 16) & 1u);   // RNE (finite inputs)
    return (unsigned short)(r >> 16);
}

// ---------------- fp32 -> bf16 cast kernels ----------------
__global__ __launch_bounds__(256)
void cvt_kernel(const float* __restrict__ src, unsigned short* __restrict__ dst, int n8)
{
    int i = blockIdx.x * 256 + threadIdx.x;
    if (i >= n8) return;
    const float4* s = (const float4*)src + (size_t)i * 2;
    float4 a = s[0], b = s[1];
    bf16x8 o;
    o[0] = (short)f2bf(a.x); o[1] = (short)f2bf(a.y);
    o[2] = (short)f2bf(a.z); o[3] = (short)f2bf(a.w);
    o[4] = (short)f2bf(b.x); o[5] = (short)f2bf(b.y);
    o[6] = (short)f2bf(b.z); o[7] = (short)f2bf(b.w);
    *(bf16x8*)(dst + (size_t)i * 8) = o;
}

__global__ __launch_bounds__(256)
void cvt4_kernel(const float* __restrict__ w0, const float* __restrict__ w1,
                 const float* __restrict__ w2, const float* __restrict__ w3,
                 unsigned short* __restrict__ d0, unsigned short* __restrict__ d1,
                 unsigned short* __restrict__ d2, unsigned short* __restrict__ d3,
                 int n8)
{
    int i = blockIdx.x * 256 + threadIdx.x;
    if (i >= n8) return;
    const float* w = (blockIdx.y == 0) ? w0 : (blockIdx.y == 1) ? w1
                    : (blockIdx.y == 2) ? w2 : w3;
    unsigned short* d = (blockIdx.y == 0) ? d0 : (blockIdx.y == 1) ? d1
                       : (blockIdx.y == 2) ? d2 : d3;
    const float4* s = (const float4*)w + (size_t)i * 2;
    float4 a = s[0], b = s[1];
    bf16x8 o;
    o[0] = (short)f2bf(a.x); o[1] = (short)f2bf(a.y);
    o[2] = (short)f2bf(a.z); o[3] = (short)f2bf(a.w);
    o[4] = (short)f2bf(b.x); o[5] = (short)f2bf(b.y);
    o[6] = (short)f2bf(b.z); o[7] = (short)f2bf(b.w);
    *(bf16x8*)(d + (size_t)i * 8) = o;
}

// ---------------- MFMA GEMM core: C = A (MxK) * W^T (W is NxK), bf16 ----------------
// 128x128 tile, BK=32, 4 waves (2x2), per-wave 4x4 16x16 frags.
// LDS rows padded to 40 shorts (80B) -> ~2-way max bank aliasing (free).
#define GLD 40

__device__ __forceinline__ void gemm_mfma(const unsigned short* __restrict__ A,
                                          const unsigned short* __restrict__ W,
                                          int m0, int n0, fx4 acc[4][4],
                                          unsigned short* Asl, unsigned short* Bsl)
{
    const int t = threadIdx.x;
    const int w = t >> 6, lane = t & 63;
    const int wm = w >> 1, wn = w & 1;
    const int lr = lane & 15, lg = lane >> 4;

    bf16x8 pa[2], pb[2];
    #pragma unroll
    for (int q = 0; q < 2; ++q) {               // prefetch k0 = 0
        int chunk = t + q * 256, row = chunk >> 2, c = chunk & 3;
        pa[q] = *(const bf16x8*)(A + (size_t)(m0 + row) * Kd + c * 8);
        pb[q] = *(const bf16x8*)(W + (size_t)(n0 + row) * Kd + c * 8);
    }
    for (int k0 = 0; k0 < Kd; k0 += 32) {
        __syncthreads();                        // prev tile's LDS reads done
        #pragma unroll
        for (int q = 0; q < 2; ++q) {
            int chunk = t + q * 256, row = chunk >> 2, c = chunk & 3;
            *(bf16x8*)(Asl + row * GLD + c * 8) = pa[q];
            *(bf16x8*)(Bsl + row * GLD + c * 8) = pb[q];
        }
        __syncthreads();
        if (k0 + 32 < Kd) {                     // issue next-tile loads early (hide under MFMA)
            #pragma unroll
            for (int q = 0; q < 2; ++q) {
                int chunk = t + q * 256, row = chunk >> 2, c = chunk & 3;
                pa[q] = *(const bf16x8*)(A + (size_t)(m0 + row) * Kd + k0 + 32 + c * 8);
                pb[q] = *(const bf16x8*)(W + (size_t)(n0 + row) * Kd + k0 + 32 + c * 8);
            }
        }
        bf16x8 af[4], bf[4];
        #pragma unroll
        for (int i = 0; i < 4; ++i)
            af[i] = *(const bf16x8*)(Asl + (wm * 64 + i * 16 + lr) * GLD + lg * 8);
        #pragma unroll
        for (int j = 0; j < 4; ++j)
            bf[j] = *(const bf16x8*)(Bsl + (wn * 64 + j * 16 + lr) * GLD + lg * 8);
        #pragma unroll
        for (int i = 0; i < 4; ++i)
            #pragma unroll
            for (int j = 0; j < 4; ++j)
                acc[i][j] = __builtin_amdgcn_mfma_f32_16x16x32_bf16(af[i], bf[j], acc[i][j], 0, 0, 0);
    }
}

// ---------------- QKV projection + RoPE ----------------
// Q/K -> (b,h,s,d) bf16 with RoPE; V -> (b,h,d,s) bf16 (pre-transposed for PV).
__global__ __launch_bounds__(256)
void qkv_kernel(const unsigned short* __restrict__ xb,
                const unsigned short* __restrict__ wq, const unsigned short* __restrict__ wk,
                const unsigned short* __restrict__ wv,
                const float* __restrict__ fcos, const float* __restrict__ fsin,
                unsigned short* __restrict__ qb, unsigned short* __restrict__ kb,
                unsigned short* __restrict__ vtb)
{
    __shared__ unsigned short Asl[128 * GLD];
    __shared__ unsigned short Bsl[128 * GLD];
    const int mode = blockIdx.z;
    const unsigned short* W = (mode == 0) ? wq : (mode == 1) ? wk : wv;
    const int m0 = blockIdx.x * 128, n0 = blockIdx.y * 128;

    fx4 zero = {0.f, 0.f, 0.f, 0.f};
    fx4 acc[4][4];
    #pragma unroll
    for (int i = 0; i < 4; ++i)
        #pragma unroll
        for (int j = 0; j < 4; ++j) acc[i][j] = zero;

    gemm_mfma(xb, W, m0, n0, acc, Asl, Bsl);

    const int t = threadIdx.x, w = t >> 6, lane = t & 63;
    const int wm = w >> 1, wn = w & 1, lr = lane & 15, lg = lane >> 4;
    const int h = n0 >> 7;                      // whole block inside one head
    if (mode < 2) {
        unsigned short* outp = (mode == 0) ? qb : kb;
        #pragma unroll
        for (int i = 0; i < 4; ++i) {
            int mbase = m0 + wm * 64 + i * 16 + lg * 4;
            #pragma unroll
            for (int j = 0; j < 4; ++j) {
                int d = wn * 64 + j * 16 + lr;  // within-head index; parity == lane parity
                #pragma unroll
                for (int r = 0; r < 4; ++r) {
                    int m = mbase + r, b = m >> 11, s = m & (Sn - 1);
                    float vv = acc[i][j][r];
                    float other = __shfl_xor(vv, 1, 64);   // partner holds d^1
                    float c  = fcos[s * (HDn / 2) + (d >> 1)];
                    float sn = fsin[s * (HDn / 2) + (d >> 1)];
                    float res = (d & 1) ? (other * sn + vv * c) : (vv * c - other * sn);
                    outp[(((size_t)b * NHn + h) * Sn + s) * HDn + d] = f2bf(res);
                }
            }
        }
    } else {
        #pragma unroll
        for (int i = 0; i < 4; ++i) {
            int mbase = m0 + wm * 64 + i * 16 + lg * 4;
            int b = mbase >> 11, s = mbase & (Sn - 1);    // 4 rows stay in one b
            #pragma unroll
            for (int j = 0; j < 4; ++j) {
                int d = wn * 64 + j * 16 + lr;
                ushort4 pk;
                pk.x = f2bf(acc[i][j][0]); pk.y = f2bf(acc[i][j][1]);
                pk.z = f2bf(acc[i][j][2]); pk.w = f2bf(acc[i][j][3]);
                *(ushort4*)(vtb + (((size_t)b * NHn + h) * HDn + d) * Sn + s) = pk;
            }
        }
    }
}

// ---------------- Output projection (fp32 out) ----------------
__global__ __launch_bounds__(256)
void oproj_kernel(const unsigned short* __restrict__ attnb,
                  const unsigned short* __restrict__ wob, float* __restrict__ out)
{
    __shared__ unsigned short Asl[128 * GLD];
    __shared__ unsigned short Bsl[128 * GLD];
    const int m0 = blockIdx.x * 128, n0 = blockIdx.y * 128;
    fx4 zero = {0.f, 0.f, 0.f, 0.f};
    fx4 acc[4][4];
    #pragma unroll
    for (int i = 0; i < 4; ++i)
        #pragma unroll
        for (int j = 0; j < 4; ++j) acc[i][j] = zero;

    gemm_mfma(attnb, wob, m0, n0, acc, Asl, Bsl);

    const int t = threadIdx.x, w = t >> 6, lane = t & 63;
    const int wm = w >> 1, wn = w & 1, lr = lane & 15, lg = lane >> 4;
    #pragma unroll
    for (int i = 0; i < 4; ++i) {
        #pragma unroll
        for (int r = 0; r < 4; ++r) {
            int m = m0 + wm * 64 + i * 16 + lg * 4 + r;
            #pragma unroll
            for (int j = 0; j < 4; ++j)
                out[(size_t)m * Hn + n0 + wn * 64 + j * 16 + lr] = acc[i][j][r];
        }
    }
}

// ---------------- Flash attention, bf16 MFMA + fp32 online softmax ----------------
// Block: 4 waves x 16 q-rows = 64 q; BKV = 64. K tile [64][128]b16 (rows 272B),
// Vt tile [128][64]b16 (rows 144B), per-wave P [16][64]b16 (rows 136B). 43.5KB LDS.
#define KROW 136   // shorts per K-tile row
#define VROW 72    // shorts per Vt-tile row
#define PROW 68    // shorts per P row

__global__ __launch_bounds__(256)
void attn_kernel(const unsigned short* __restrict__ qb,
                 const unsigned short* __restrict__ kb,
                 const unsigned short* __restrict__ vtb,
                 const int* __restrict__ pmask, unsigned short* __restrict__ attnb)
{
    __shared__ unsigned short Ksl[64 * KROW];
    __shared__ unsigned short Vsl[128 * VROW];
    __shared__ unsigned short Psl[4 * 16 * PROW];

    const int qt = blockIdx.x, h = blockIdx.y, b = blockIdx.z;
    const int q0 = qt * 64;
    const size_t base = ((size_t)b * NHn + h) * Sn * HDn;
    const unsigned short* Qp = qb + base;
    const unsigned short* Kp = kb + base;
    const unsigned short* Vt = vtb + base;      // (d, s)
    const int t = threadIdx.x, w = t >> 6, lane = t & 63;
    const int lr = lane & 15, lg = lane >> 4;

    // Q fragments in registers: wave w owns rows q0 + w*16 .. +15
    bf16x8 qf[4];
    #pragma unroll
    for (int kf = 0; kf < 4; ++kf)
        qf[kf] = *(const bf16x8*)(Qp + (size_t)(q0 + w * 16 + lr) * HDn + kf * 32 + lg * 8);

    fx4 zero = {0.f, 0.f, 0.f, 0.f};
    fx4 oacc[8];
    #pragma unroll
    for (int j = 0; j < 8; ++j) oacc[j] = zero;
    float mrow[4] = {-1e30f, -1e30f, -1e30f, -1e30f};
    float lsum[4] = {0.f, 0.f, 0.f, 0.f};
    const float scale = 0.08838834764831845f;   // 1/sqrt(128)

    // K tile: 64x128 shorts = 1024 chunks (4/thread).
    // Vt tile: 128x64 shorts = 1024 chunks (4/thread).  <-- was 2/thread: half of
    // Vsl (cols 32..63) stayed uninitialized -> 1e28 garbage. Fixed.
    bf16x8 kreg[4], vreg[4];
    #pragma unroll
    for (int q = 0; q < 4; ++q) {
        int chunk = t + q * 256, row = chunk >> 4, c = chunk & 15;
        kreg[q] = *(const bf16x8*)(Kp + (size_t)row * HDn + c * 8);
    }
    #pragma unroll
    for (int q = 0; q < 4; ++q) {
        int chunk = t + q * 256, row = chunk >> 3, c = chunk & 7;
        vreg[q] = *(const bf16x8*)(Vt + (size_t)row * Sn + c * 8);
    }

    const int ntiles = qt + 1;
    for (int kt = 0; kt < ntiles; ++kt) {
        const int kv0 = kt * 64;
        __syncthreads();
        #pragma unroll
        for (int q = 0; q < 4; ++q) {
            int chunk = t + q * 256, row = chunk >> 4, c = chunk & 15;
            *(bf16x8*)(Ksl + row * KROW + c * 8) = kreg[q];
        }
        #pragma unroll
        for (int q = 0; q < 4; ++q) {
            int chunk = t + q * 256, row = chunk >> 3, c = chunk & 7;
            *(bf16x8*)(Vsl + row * VROW + c * 8) = vreg[q];
        }
        __syncthreads();
        if (kt + 1 < ntiles) {                  // prefetch next tile during compute
            #pragma unroll
            for (int q = 0; q < 4; ++q) {
                int chunk = t + q * 256, row = chunk >> 4, c = chunk & 15;
                kreg[q] = *(const bf16x8*)(Kp + (size_t)(kv0 + 64 + row) * HDn + c * 8);
            }
            #pragma unroll
            for (int q = 0; q < 4; ++q) {
                int chunk = t + q * 256, row = chunk >> 3, c = chunk & 7;
                vreg[q] = *(const bf16x8*)(Vt + (size_t)row * Sn + kv0 + 64 + c * 8);
            }
        }

        // QK^T: S[q = w*16+lg*4+r][kv = kv0+nf*16+lr]
        fx4 sc[4];
        #pragma unroll
        for (int nf = 0; nf < 4; ++nf) {
            fx4 z = zero;
            #pragma unroll
            for (int kf = 0; kf < 4; ++kf) {
                bf16x8 kfr = *(const bf16x8*)(Ksl + (nf * 16 + lr) * KROW + kf * 32 + lg * 8);
                z = __builtin_amdgcn_mfma_f32_16x16x32_bf16(qf[kf], kfr, z, 0, 0, 0);
            }
            sc[nf] = z;
        }

        // mask + online softmax (fp32)
        float pmv[4];
        #pragma unroll
        for (int nf = 0; nf < 4; ++nf)
            pmv[nf] = pmask[b * Sn + kv0 + nf * 16 + lr] ? 0.f : -10000.f;
        float tmax[4];
        #pragma unroll
        for (int r = 0; r < 4; ++r) {
            int qrow = q0 + w * 16 + lg * 4 + r;
            float mx = -1e30f;
            #pragma unroll
            for (int nf = 0; nf < 4; ++nf) {
                int kg = kv0 + nf * 16 + lr;
                float v = sc[nf][r] * scale + pmv[nf] + ((kg > qrow) ? -1e9f : 0.f);
                sc[nf][r] = v;
                mx = fmaxf(mx, v);
            }
            tmax[r] = mx;
        }
        #pragma unroll
        for (int off = 1; off < 16; off <<= 1)
            #pragma unroll
            for (int r = 0; r < 4; ++r)
                tmax[r] = fmaxf(tmax[r], __shfl_xor(tmax[r], off, 64));
        float psum[4];
        #pragma unroll
        for (int r = 0; r < 4; ++r) {
            float mnew = fmaxf(mrow[r], tmax[r]);
            float sf = __expf(mrow[r] - mnew);
            mrow[r] = mnew;
            lsum[r] *= sf;
            float ps = 0.f;
            #pragma unroll
            for (int nf = 0; nf < 4; ++nf) {
                float p = __expf(sc[nf][r] - mnew);
                sc[nf][r] = p;
                ps += p;
            }
            psum[r] = ps;
            #pragma unroll
            for (int j = 0; j < 8; ++j) oacc[j][r] *= sf;
        }
        #pragma unroll
        for (int off = 1; off < 16; off <<= 1)
            #pragma unroll
            for (int r = 0; r < 4; ++r)
                psum[r] += __shfl_xor(psum[r], off, 64);
        #pragma unroll
        for (int r = 0; r < 4; ++r) lsum[r] += psum[r];

        // P -> per-wave LDS (bf16), then PV
        unsigned short* Pw = Psl + w * 16 * PROW;
        #pragma unroll
        for (int nf = 0; nf < 4; ++nf)
            #pragma unroll
            for (int r = 0; r < 4; ++r)
                Pw[(lg * 4 + r) * PROW + nf * 16 + lr] = f2bf(sc[nf][r]);
        // (wave-local LDS RAW; compiler inserts lgkmcnt)
        #pragma unroll
        for (int kf2 = 0; kf2 < 2; ++kf2) {
            bf16x8 pf = *(const bf16x8*)(Pw + lr * PROW + kf2 * 32 + lg * 8);
            #pragma unroll
            for (int j = 0; j < 8; ++j) {
                bf16x8 vf = *(const bf16x8*)(Vsl + (j * 16 + lr) * VROW + kf2 * 32 + lg * 8);
                oacc[j] = __builtin_amdgcn_mfma_f32_16x16x32_bf16(pf, vf, oacc[j], 0, 0, 0);
            }
        }
    }

    // normalize + write (b, s, h*HD + d) bf16
    #pragma unroll
    for (int j = 0; j < 8; ++j) {
        int d = j * 16 + lr;
        #pragma unroll
        for (int r = 0; r < 4; ++r) {
            int s = q0 + w * 16 + lg * 4 + r;
            attnb[((size_t)b * Sn + s) * Hn + h * HDn + d] = f2bf(oacc[j][r] / lsum[r]);
        }
    }
}

// ---------------- launch ----------------
extern "C" void kernel_launch(void* const* d_in, const int* in_sizes, int n_in,
                              void* d_out, int out_size, void* d_ws, size_t ws_size,
                              hipStream_t stream)
{
    const float* x     = (const float*)d_in[0];
    const float* fcos  = (const float*)d_in[1];
    const float* fsin  = (const float*)d_in[2];
    const int*   pmask = (const int*)d_in[3];
    const float* Wq    = (const float*)d_in[4];
    const float* Wk    = (const float*)d_in[5];
    const float* Wv    = (const float*)d_in[6];
    const float* Wo    = (const float*)d_in[7];
    float* out = (float*)d_out;
    (void)in_sizes; (void)n_in; (void)out_size; (void)ws_size;

    const size_t NX = (size_t)Mn * Hn;        // 8,388,608
    const size_t NW = (size_t)Hn * Hn;        // 4,194,304
    unsigned short* xb   = (unsigned short*)d_ws;
    unsigned short* wqb  = xb  + NX;
    unsigned short* wkb  = wqb + NW;
    unsigned short* wvb  = wkb + NW;
    unsigned short* wob  = wvb + NW;
    unsigned short* qb   = wob + NW;
    unsigned short* kb   = qb  + NX;
    unsigned short* vtb  = kb  + NX;
    unsigned short* attnb= vtb + NX;          // total ~117 MB

    cvt_kernel<<<dim3((int)(NX / 8 / 256)), 256, 0, stream>>>(x, xb, (int)(NX / 8));
    cvt4_kernel<<<dim3((int)(NW / 8 / 256), 4), 256, 0, stream>>>(
        Wq, Wk, Wv, Wo, wqb, wkb, wvb, wob, (int)(NW / 8));
    qkv_kernel<<<dim3(Mn / 128, Hn / 128, 3), 256, 0, stream>>>(
        xb, wqb, wkb, wvb, fcos, fsin, qb, kb, vtb);
    attn_kernel<<<dim3(Sn / 64, NHn, Bn), 256, 0, stream>>>(qb, kb, vtb, pmask, attnb);
    oproj_kernel<<<dim3(Mn / 128, Hn / 128), 256, 0, stream>>>(attnb, wob, out);
}

// Round 4
// 442.742 us; speedup vs baseline: 7.6482x; 1.2033x over previous
//
#include <hip/hip_runtime.h>
#include <math.h>

// Problem constants
#define Bn  2
#define Sn  2048
#define Hn  2048
#define NHn 16
#define HDn 128
#define Mn  (Bn * Sn)   // 4096
#define Kd  Hn          // 2048

typedef __attribute__((ext_vector_type(8))) short bf16x8;   // 8 bf16 in 4 VGPRs
typedef __attribute__((ext_vector_type(4))) float fx4;

__device__ __forceinline__ unsigned short f2bf(float f) {
    union { float f; unsigned u; } v; v.f = f;
    unsigned r = v.u + 0x7fffu + ((v.u >> 16) & 1u);   // RNE (finite inputs)
    return (unsigned short)(r >> 16);
}

// async global->LDS, 16B per lane; LDS dest = wave-uniform base + lane*16
__device__ __forceinline__ void gload16(const unsigned short* g, unsigned short* l) {
    __builtin_amdgcn_global_load_lds(
        (const __attribute__((address_space(1))) unsigned int*)g,
        (__attribute__((address_space(3))) unsigned int*)l, 16, 0, 0);
}

// ---------------- fp32 -> bf16 cast kernels ----------------
__global__ __launch_bounds__(256)
void cvt_kernel(const float* __restrict__ src, unsigned short* __restrict__ dst, int n8)
{
    int i = blockIdx.x * 256 + threadIdx.x;
    if (i >= n8) return;
    const float4* s = (const float4*)src + (size_t)i * 2;
    float4 a = s[0], b = s[1];
    bf16x8 o;
    o[0] = (short)f2bf(a.x); o[1] = (short)f2bf(a.y);
    o[2] = (short)f2bf(a.z); o[3] = (short)f2bf(a.w);
    o[4] = (short)f2bf(b.x); o[5] = (short)f2bf(b.y);
    o[6] = (short)f2bf(b.z); o[7] = (short)f2bf(b.w);
    *(bf16x8*)(dst + (size_t)i * 8) = o;
}

__global__ __launch_bounds__(256)
void cvt4_kernel(const float* __restrict__ w0, const float* __restrict__ w1,
                 const float* __restrict__ w2, const float* __restrict__ w3,
                 unsigned short* __restrict__ d0, unsigned short* __restrict__ d1,
                 unsigned short* __restrict__ d2, unsigned short* __restrict__ d3,
                 int n8)
{
    int i = blockIdx.x * 256 + threadIdx.x;
    if (i >= n8) return;
    const float* w = (blockIdx.y == 0) ? w0 : (blockIdx.y == 1) ? w1
                    : (blockIdx.y == 2) ? w2 : w3;
    unsigned short* d = (blockIdx.y == 0) ? d0 : (blockIdx.y == 1) ? d1
                       : (blockIdx.y == 2) ? d2 : d3;
    const float4* s = (const float4*)w + (size_t)i * 2;
    float4 a = s[0], b = s[1];
    bf16x8 o;
    o[0] = (short)f2bf(a.x); o[1] = (short)f2bf(a.y);
    o[2] = (short)f2bf(a.z); o[3] = (short)f2bf(a.w);
    o[4] = (short)f2bf(b.x); o[5] = (short)f2bf(b.y);
    o[6] = (short)f2bf(b.z); o[7] = (short)f2bf(b.w);
    *(bf16x8*)(d + (size_t)i * 8) = o;
}

// ---------------- MFMA GEMM core (m97 structure): C = A (MxK) * W^T ----------------
// 128x128 tile, BK=32, 4 waves (2x2), global_load_lds width-16 staging into
// LINEAR LDS [128][32] bf16 (8KB per operand). 2 barriers per K-step.
__device__ __forceinline__ void gemm_mfma(const unsigned short* __restrict__ A,
                                          const unsigned short* __restrict__ W,
                                          int m0, int n0, fx4 acc[4][4],
                                          unsigned short* Asl, unsigned short* Bsl)
{
    const int t = threadIdx.x;
    const int w = t >> 6, lane = t & 63;
    const int wm = w >> 1, wn = w & 1;
    const int lr = lane & 15, lg = lane >> 4;

    // staging: wave w owns rows [w*32, w*32+32); lane -> (row = lane>>2, chunk = lane&3)
    const int srow = w * 32 + (lane >> 2);
    const int scol = (lane & 3) * 8;
    const unsigned short* Ag0 = A + (size_t)(m0 + srow) * Kd + scol;
    const unsigned short* Ag1 = Ag0 + (size_t)16 * Kd;
    const unsigned short* Bg0 = W + (size_t)(n0 + srow) * Kd + scol;
    const unsigned short* Bg1 = Bg0 + (size_t)16 * Kd;
    unsigned short* Ad0 = Asl + w * 1024;        // 32 rows * 32 shorts/row
    unsigned short* Ad1 = Asl + w * 1024 + 512;
    unsigned short* Bd0 = Bsl + w * 1024;
    unsigned short* Bd1 = Bsl + w * 1024 + 512;

    for (int k0 = 0; k0 < Kd; k0 += 32) {
        __syncthreads();                // previous iteration's ds_reads complete
        gload16(Ag0 + k0, Ad0);
        gload16(Ag1 + k0, Ad1);
        gload16(Bg0 + k0, Bd0);
        gload16(Bg1 + k0, Bd1);
        __syncthreads();                // implicit vmcnt(0) drain -> LDS ready

        bf16x8 af[4], bfr[4];
        #pragma unroll
        for (int i = 0; i < 4; ++i)
            af[i] = *(const bf16x8*)(Asl + (wm * 64 + i * 16 + lr) * 32 + lg * 8);
        #pragma unroll
        for (int j = 0; j < 4; ++j)
            bfr[j] = *(const bf16x8*)(Bsl + (wn * 64 + j * 16 + lr) * 32 + lg * 8);
        #pragma unroll
        for (int i = 0; i < 4; ++i)
            #pragma unroll
            for (int j = 0; j < 4; ++j)
                acc[i][j] = __builtin_amdgcn_mfma_f32_16x16x32_bf16(af[i], bfr[j], acc[i][j], 0, 0, 0);
    }
}

// ---------------- QKV projection + RoPE ----------------
__global__ __launch_bounds__(256)
void qkv_kernel(const unsigned short* __restrict__ xb,
                const unsigned short* __restrict__ wq, const unsigned short* __restrict__ wk,
                const unsigned short* __restrict__ wv,
                const float* __restrict__ fcos, const float* __restrict__ fsin,
                unsigned short* __restrict__ qb, unsigned short* __restrict__ kb,
                unsigned short* __restrict__ vtb)
{
    __shared__ unsigned short Asl[128 * 32];
    __shared__ unsigned short Bsl[128 * 32];
    const int mode = blockIdx.z;
    const unsigned short* W = (mode == 0) ? wq : (mode == 1) ? wk : wv;
    const int m0 = blockIdx.x * 128, n0 = blockIdx.y * 128;

    fx4 zero = {0.f, 0.f, 0.f, 0.f};
    fx4 acc[4][4];
    #pragma unroll
    for (int i = 0; i < 4; ++i)
        #pragma unroll
        for (int j = 0; j < 4; ++j) acc[i][j] = zero;

    gemm_mfma(xb, W, m0, n0, acc, Asl, Bsl);

    const int t = threadIdx.x, w = t >> 6, lane = t & 63;
    const int wm = w >> 1, wn = w & 1, lr = lane & 15, lg = lane >> 4;
    const int h = n0 >> 7;                      // whole block inside one head
    if (mode < 2) {
        unsigned short* outp = (mode == 0) ? qb : kb;
        #pragma unroll
        for (int i = 0; i < 4; ++i) {
            int mbase = m0 + wm * 64 + i * 16 + lg * 4;
            #pragma unroll
            for (int j = 0; j < 4; ++j) {
                int d = wn * 64 + j * 16 + lr;  // within-head index; parity == lane parity
                #pragma unroll
                for (int r = 0; r < 4; ++r) {
                    int m = mbase + r, b = m >> 11, s = m & (Sn - 1);
                    float vv = acc[i][j][r];
                    float other = __shfl_xor(vv, 1, 64);   // partner holds d^1
                    float c  = fcos[s * (HDn / 2) + (d >> 1)];
                    float sn = fsin[s * (HDn / 2) + (d >> 1)];
                    float res = (d & 1) ? (other * sn + vv * c) : (vv * c - other * sn);
                    outp[(((size_t)b * NHn + h) * Sn + s) * HDn + d] = f2bf(res);
                }
            }
        }
    } else {
        #pragma unroll
        for (int i = 0; i < 4; ++i) {
            int mbase = m0 + wm * 64 + i * 16 + lg * 4;
            int b = mbase >> 11, s = mbase & (Sn - 1);    // 4 rows stay in one b
            #pragma unroll
            for (int j = 0; j < 4; ++j) {
                int d = wn * 64 + j * 16 + lr;
                ushort4 pk;
                pk.x = f2bf(acc[i][j][0]); pk.y = f2bf(acc[i][j][1]);
                pk.z = f2bf(acc[i][j][2]); pk.w = f2bf(acc[i][j][3]);
                *(ushort4*)(vtb + (((size_t)b * NHn + h) * HDn + d) * Sn + s) = pk;
            }
        }
    }
}

// ---------------- Output projection (fp32 out) ----------------
__global__ __launch_bounds__(256)
void oproj_kernel(const unsigned short* __restrict__ attnb,
                  const unsigned short* __restrict__ wob, float* __restrict__ out)
{
    __shared__ unsigned short Asl[128 * 32];
    __shared__ unsigned short Bsl[128 * 32];
    const int m0 = blockIdx.x * 128, n0 = blockIdx.y * 128;
    fx4 zero = {0.f, 0.f, 0.f, 0.f};
    fx4 acc[4][4];
    #pragma unroll
    for (int i = 0; i < 4; ++i)
        #pragma unroll
        for (int j = 0; j < 4; ++j) acc[i][j] = zero;

    gemm_mfma(attnb, wob, m0, n0, acc, Asl, Bsl);

    const int t = threadIdx.x, w = t >> 6, lane = t & 63;
    const int wm = w >> 1, wn = w & 1, lr = lane & 15, lg = lane >> 4;
    #pragma unroll
    for (int i = 0; i < 4; ++i) {
        #pragma unroll
        for (int r = 0; r < 4; ++r) {
            int m = m0 + wm * 64 + i * 16 + lg * 4 + r;
            #pragma unroll
            for (int j = 0; j < 4; ++j)
                out[(size_t)m * Hn + n0 + wn * 64 + j * 16 + lr] = acc[i][j][r];
        }
    }
}

// ---------------- Flash attention, bf16 MFMA + fp32 online softmax ----------------
// 4 waves x 16 q-rows = 64 q per tile; BKV = 64. Each block processes TWO Q-tiles
// (qt = pr and 31-pr) sequentially -> uniform 33 KV-tiles/block (load balance).
#define KROW 136   // shorts per K-tile row
#define VROW 72    // shorts per Vt-tile row
#define PROW 68    // shorts per P row

__global__ __launch_bounds__(256)
void attn_kernel(const unsigned short* __restrict__ qb,
                 const unsigned short* __restrict__ kb,
                 const unsigned short* __restrict__ vtb,
                 const int* __restrict__ pmask, unsigned short* __restrict__ attnb)
{
    __shared__ unsigned short Ksl[64 * KROW];
    __shared__ unsigned short Vsl[128 * VROW];
    __shared__ unsigned short Psl[4 * 16 * PROW];

    const int pr = blockIdx.x, h = blockIdx.y, b = blockIdx.z;
    const size_t base = ((size_t)b * NHn + h) * Sn * HDn;
    const unsigned short* Qp = qb + base;
    const unsigned short* Kp = kb + base;
    const unsigned short* Vt = vtb + base;      // (d, s)
    const int t = threadIdx.x, w = t >> 6, lane = t & 63;
    const int lr = lane & 15, lg = lane >> 4;
    const float scale = 0.08838834764831845f;   // 1/sqrt(128)
    fx4 zero = {0.f, 0.f, 0.f, 0.f};

    for (int ph = 0; ph < 2; ++ph) {
        const int qt = ph ? (31 - pr) : pr;
        const int q0 = qt * 64;
        const int nt = qt + 1;

        // Q fragments in registers: wave w owns rows q0 + w*16 .. +15
        bf16x8 qf[4];
        #pragma unroll
        for (int kf = 0; kf < 4; ++kf)
            qf[kf] = *(const bf16x8*)(Qp + (size_t)(q0 + w * 16 + lr) * HDn + kf * 32 + lg * 8);

        fx4 oacc[8];
        #pragma unroll
        for (int j = 0; j < 8; ++j) oacc[j] = zero;
        float mrow[4] = {-1e30f, -1e30f, -1e30f, -1e30f};
        float lsum[4] = {0.f, 0.f, 0.f, 0.f};

        // prefetch tile 0 (K: 1024 chunks, V: 1024 chunks; 4 per thread each)
        bf16x8 kreg[4], vreg[4];
        #pragma unroll
        for (int q = 0; q < 4; ++q) {
            int chunk = t + q * 256, row = chunk >> 4, c = chunk & 15;
            kreg[q] = *(const bf16x8*)(Kp + (size_t)row * HDn + c * 8);
        }
        #pragma unroll
        for (int q = 0; q < 4; ++q) {
            int chunk = t + q * 256, row = chunk >> 3, c = chunk & 7;
            vreg[q] = *(const bf16x8*)(Vt + (size_t)row * Sn + c * 8);
        }

        for (int kt = 0; kt < nt; ++kt) {
            const int kv0 = kt * 64;
            __syncthreads();
            #pragma unroll
            for (int q = 0; q < 4; ++q) {
                int chunk = t + q * 256, row = chunk >> 4, c = chunk & 15;
                *(bf16x8*)(Ksl + row * KROW + c * 8) = kreg[q];
            }
            #pragma unroll
            for (int q = 0; q < 4; ++q) {
                int chunk = t + q * 256, row = chunk >> 3, c = chunk & 7;
                *(bf16x8*)(Vsl + row * VROW + c * 8) = vreg[q];
            }
            __syncthreads();
            if (kt + 1 < nt) {                  // prefetch next tile during compute
                #pragma unroll
                for (int q = 0; q < 4; ++q) {
                    int chunk = t + q * 256, row = chunk >> 4, c = chunk & 15;
                    kreg[q] = *(const bf16x8*)(Kp + (size_t)(kv0 + 64 + row) * HDn + c * 8);
                }
                #pragma unroll
                for (int q = 0; q < 4; ++q) {
                    int chunk = t + q * 256, row = chunk >> 3, c = chunk & 7;
                    vreg[q] = *(const bf16x8*)(Vt + (size_t)row * Sn + kv0 + 64 + c * 8);
                }
            }

            // QK^T: S[q = w*16+lg*4+r][kv = kv0+nf*16+lr]
            fx4 sc[4];
            __builtin_amdgcn_s_setprio(1);
            #pragma unroll
            for (int nf = 0; nf < 4; ++nf) {
                fx4 z = zero;
                #pragma unroll
                for (int kf = 0; kf < 4; ++kf) {
                    bf16x8 kfr = *(const bf16x8*)(Ksl + (nf * 16 + lr) * KROW + kf * 32 + lg * 8);
                    z = __builtin_amdgcn_mfma_f32_16x16x32_bf16(qf[kf], kfr, z, 0, 0, 0);
                }
                sc[nf] = z;
            }
            __builtin_amdgcn_s_setprio(0);

            // mask + online softmax (fp32), defer-max (THR=8)
            float pmv[4];
            #pragma unroll
            for (int nf = 0; nf < 4; ++nf)
                pmv[nf] = pmask[b * Sn + kv0 + nf * 16 + lr] ? 0.f : -10000.f;
            float tmax[4];
            #pragma unroll
            for (int r = 0; r < 4; ++r) {
                int qrow = q0 + w * 16 + lg * 4 + r;
                float mx = -1e30f;
                #pragma unroll
                for (int nf = 0; nf < 4; ++nf) {
                    int kg = kv0 + nf * 16 + lr;
                    float v = sc[nf][r] * scale + pmv[nf] + ((kg > qrow) ? -1e9f : 0.f);
                    sc[nf][r] = v;
                    mx = fmaxf(mx, v);
                }
                tmax[r] = mx;
            }
            #pragma unroll
            for (int off = 1; off < 16; off <<= 1)
                #pragma unroll
                for (int r = 0; r < 4; ++r)
                    tmax[r] = fmaxf(tmax[r], __shfl_xor(tmax[r], off, 64));
            float grow = 0.f;
            #pragma unroll
            for (int r = 0; r < 4; ++r) grow = fmaxf(grow, tmax[r] - mrow[r]);
            if (__any(grow > 8.f)) {            // rescale only when max grew enough
                #pragma unroll
                for (int r = 0; r < 4; ++r) {
                    float mnew = fmaxf(mrow[r], tmax[r]);
                    float sf = __expf(mrow[r] - mnew);
                    mrow[r] = mnew;
                    lsum[r] *= sf;
                    #pragma unroll
                    for (int j = 0; j < 8; ++j) oacc[j][r] *= sf;
                }
            }
            float psum[4];
            #pragma unroll
            for (int r = 0; r < 4; ++r) {
                float ps = 0.f;
                #pragma unroll
                for (int nf = 0; nf < 4; ++nf) {
                    float p = __expf(sc[nf][r] - mrow[r]);   // bounded by e^8 when deferred
                    sc[nf][r] = p;
                    ps += p;
                }
                psum[r] = ps;
            }
            #pragma unroll
            for (int off = 1; off < 16; off <<= 1)
                #pragma unroll
                for (int r = 0; r < 4; ++r)
                    psum[r] += __shfl_xor(psum[r], off, 64);
            #pragma unroll
            for (int r = 0; r < 4; ++r) lsum[r] += psum[r];

            // P -> per-wave LDS (bf16), then PV
            unsigned short* Pw = Psl + w * 16 * PROW;
            #pragma unroll
            for (int nf = 0; nf < 4; ++nf)
                #pragma unroll
                for (int r = 0; r < 4; ++r)
                    Pw[(lg * 4 + r) * PROW + nf * 16 + lr] = f2bf(sc[nf][r]);
            __builtin_amdgcn_s_setprio(1);
            #pragma unroll
            for (int kf2 = 0; kf2 < 2; ++kf2) {
                bf16x8 pf = *(const bf16x8*)(Pw + lr * PROW + kf2 * 32 + lg * 8);
                #pragma unroll
                for (int j = 0; j < 8; ++j) {
                    bf16x8 vf = *(const bf16x8*)(Vsl + (j * 16 + lr) * VROW + kf2 * 32 + lg * 8);
                    oacc[j] = __builtin_amdgcn_mfma_f32_16x16x32_bf16(pf, vf, oacc[j], 0, 0, 0);
                }
            }
            __builtin_amdgcn_s_setprio(0);
        }

        // normalize + write (b, s, h*HD + d) bf16
        #pragma unroll
        for (int j = 0; j < 8; ++j) {
            int d = j * 16 + lr;
            #pragma unroll
            for (int r = 0; r < 4; ++r) {
                int s = q0 + w * 16 + lg * 4 + r;
                attnb[((size_t)b * Sn + s) * Hn + h * HDn + d] = f2bf(oacc[j][r] / lsum[r]);
            }
        }
        __syncthreads();   // protect Ksl/Vsl before next phase restages
    }
}

// ---------------- launch ----------------
extern "C" void kernel_launch(void* const* d_in, const int* in_sizes, int n_in,
                              void* d_out, int out_size, void* d_ws, size_t ws_size,
                              hipStream_t stream)
{
    const float* x     = (const float*)d_in[0];
    const float* fcos  = (const float*)d_in[1];
    const float* fsin  = (const float*)d_in[2];
    const int*   pmask = (const int*)d_in[3];
    const float* Wq    = (const float*)d_in[4];
    const float* Wk    = (const float*)d_in[5];
    const float* Wv    = (const float*)d_in[6];
    const float* Wo    = (const float*)d_in[7];
    float* out = (float*)d_out;
    (void)in_sizes; (void)n_in; (void)out_size; (void)ws_size;

    const size_t NX = (size_t)Mn * Hn;        // 8,388,608
    const size_t NW = (size_t)Hn * Hn;        // 4,194,304
    unsigned short* xb   = (unsigned short*)d_ws;
    unsigned short* wqb  = xb  + NX;
    unsigned short* wkb  = wqb + NW;
    unsigned short* wvb  = wkb + NW;
    unsigned short* wob  = wvb + NW;
    unsigned short* qb   = wob + NW;
    unsigned short* kb   = qb  + NX;
    unsigned short* vtb  = kb  + NX;
    unsigned short* attnb= vtb + NX;          // total ~117 MB

    cvt_kernel<<<dim3((int)(NX / 8 / 256)), 256, 0, stream>>>(x, xb, (int)(NX / 8));
    cvt4_kernel<<<dim3((int)(NW / 8 / 256), 4), 256, 0, stream>>>(
        Wq, Wk, Wv, Wo, wqb, wkb, wvb, wob, (int)(NW / 8));
    qkv_kernel<<<dim3(Mn / 128, Hn / 128, 3), 256, 0, stream>>>(
        xb, wqb, wkb, wvb, fcos, fsin, qb, kb, vtb);
    attn_kernel<<<dim3(16, NHn, Bn), 256, 0, stream>>>(qb, kb, vtb, pmask, attnb);
    oproj_kernel<<<dim3(Mn / 128, Hn / 128), 256, 0, stream>>>(attnb, wob, out);
}